// Round 1
// baseline (626.134 us; speedup 1.0000x reference)
//
#include <hip/hip_runtime.h>
#include <cmath>

// Problem constants: B=8, C=64, H=256, W=256, k=3, pad=1 (H only)
#define HW 65536      // 256*256
#define NPIX 524288   // 8*65536
#define NPER 524288   // values per channel for BN: B*H*W

// ws layout (floats):
//  om  : [8][9][256][256]  offset-conv output (dy0-2, dx0-2, sigmoid mask0-2)
//  sums: [128]             per-channel sum[64], sumsq[64]
//  wdT : [3][64][64]       w_dcn transposed to [kh][c][o]
//  wfT : [192][12]         w_off transposed to [c*3+kh][o], padded 9->12
#define OM_OFF   0
#define SUMS_OFF 4718592
#define WDT_OFF  4718720
#define WFT_OFF  4731008

__global__ __launch_bounds__(256) void transpose_wts(
    const float* __restrict__ w_off, const float* __restrict__ w_dcn,
    float* __restrict__ wfT, float* __restrict__ wdT) {
  int i = blockIdx.x * 256 + threadIdx.x;
  if (i < 12288) {
    int o = i & 63, c = (i >> 6) & 63, kh = i >> 12;
    wdT[(((kh << 6) + c) << 6) + o] = w_dcn[(o * 64 + c) * 3 + kh];
  }
  if (i < 1728) {
    int o = i % 9, ck = i / 9;            // ck = c*3+kh
    int c = ck / 3, kh = ck % 3;
    wfT[ck * 12 + o] = w_off[(o * 64 + c) * 3 + kh];
  }
}

// Offset conv: om[b,o,h,w] = b_off[o] + sum_c sum_kh xp[b,c,h+kh,w]*w_off[o,c,kh]
// xp row hp maps to x row hp-1 (zero outside [0,255]).
__global__ __launch_bounds__(256) void offset_conv(
    const float* __restrict__ x, const float* __restrict__ wfT,
    const float* __restrict__ b_off, float* __restrict__ om) {
  __shared__ float wf[2304];
  for (int i = threadIdx.x; i < 576; i += 256)
    ((float4*)wf)[i] = ((const float4*)wfT)[i];
  __syncthreads();

  int idx = blockIdx.x * 256 + threadIdx.x;
  int w = idx & 255, h = (idx >> 8) & 255, b = idx >> 16;

  float acc[9];
#pragma unroll
  for (int o = 0; o < 9; ++o) acc[o] = b_off[o];

  const float* xb = x + (size_t)(b << 6) * HW + w;
  for (int c = 0; c < 64; ++c) {
    const float* xc = xb + c * HW;
#pragma unroll
    for (int kh = 0; kh < 3; ++kh) {
      int hr = h + kh - 1;                      // x row
      int hc = min(max(hr, 0), 255);
      float v = xc[hc * 256];
      v = (hr >= 0 && hr < 256) ? v : 0.f;
      const float* wr = &wf[(c * 3 + kh) * 12];
#pragma unroll
      for (int o = 0; o < 9; ++o) acc[o] = fmaf(v, wr[o], acc[o]);
    }
  }

  float* omb = om + (size_t)b * (9 * HW) + h * 256 + w;
#pragma unroll
  for (int o = 0; o < 6; ++o) omb[o * HW] = acc[o];
#pragma unroll
  for (int o = 6; o < 9; ++o) omb[o * HW] = 1.f / (1.f + expf(-acc[o]));
}

// Main: bilinear sample xp at (h+kh+dy, w+dx), *mask, then
// out[b,o,h,w] = b_dcn[o] + sum_{kh,c} s[kh,c] * w_dcn[o,c,kh]   (pre-BN)
__global__ __launch_bounds__(256) void dcn_main(
    const float* __restrict__ x, const float* __restrict__ om,
    const float* __restrict__ wdT, const float* __restrict__ b_dcn,
    float* __restrict__ out) {
  __shared__ float wd[12288];
  for (int i = threadIdx.x; i < 3072; i += 256)
    ((float4*)wd)[i] = ((const float4*)wdT)[i];
  __syncthreads();

  int idx = blockIdx.x * 256 + threadIdx.x;
  int w = idx & 255, h = (idx >> 8) & 255, b = idx >> 16;

  float acc[64];
#pragma unroll
  for (int o = 0; o < 64; ++o) acc[o] = 0.f;

  const float* omb = om + (size_t)b * (9 * HW) + h * 256 + w;
  const float* xb = x + (size_t)(b << 6) * HW;

#pragma unroll
  for (int kh = 0; kh < 3; ++kh) {
    float dy = omb[kh * HW];
    float dxv = omb[(3 + kh) * HW];
    float m = omb[(6 + kh) * HW];
    float yf = (float)(h + kh) + dy;          // xp coords [~0, ~257]
    float xf = (float)w + dxv;
    float y0f = floorf(yf), x0f = floorf(xf);
    int iy0 = (int)y0f, ix0 = (int)x0f;
    float wy1 = yf - y0f, wy0 = 1.f - wy1;
    float wx1 = xf - x0f, wx0 = 1.f - wx1;
    // x-array rows: r = yi - 1. Contribution nonzero only if r,c in-bounds of x
    // (covers both ref validity and the zero pad rows of xp).
    int r0 = iy0 - 1, r1 = iy0, c0 = ix0, c1 = ix0 + 1;
    bool vr0 = (r0 >= 0) & (r0 < 256), vr1 = (r1 >= 0) & (r1 < 256);
    bool vc0 = (c0 >= 0) & (c0 < 256), vc1 = (c1 >= 0) & (c1 < 256);
    float w00 = (vr0 & vc0) ? wy0 * wx0 * m : 0.f;
    float w01 = (vr0 & vc1) ? wy0 * wx1 * m : 0.f;
    float w10 = (vr1 & vc0) ? wy1 * wx0 * m : 0.f;
    float w11 = (vr1 & vc1) ? wy1 * wx1 * m : 0.f;
    int cr0 = min(max(r0, 0), 255), cr1 = min(max(r1, 0), 255);
    int cc0 = min(max(c0, 0), 255), cc1 = min(max(c1, 0), 255);
    int o00 = cr0 * 256 + cc0, o01 = cr0 * 256 + cc1;
    int o10 = cr1 * 256 + cc0, o11 = cr1 * 256 + cc1;

    for (int c = 0; c < 64; ++c) {
      const float* xp = xb + c * HW;
      float s = xp[o00] * w00 + xp[o01] * w01 + xp[o10] * w10 + xp[o11] * w11;
      const float4* wv = (const float4*)&wd[(((kh << 6) + c) << 6)];
#pragma unroll
      for (int o4 = 0; o4 < 16; ++o4) {
        float4 q = wv[o4];
        acc[o4 * 4 + 0] = fmaf(s, q.x, acc[o4 * 4 + 0]);
        acc[o4 * 4 + 1] = fmaf(s, q.y, acc[o4 * 4 + 1]);
        acc[o4 * 4 + 2] = fmaf(s, q.z, acc[o4 * 4 + 2]);
        acc[o4 * 4 + 3] = fmaf(s, q.w, acc[o4 * 4 + 3]);
      }
    }
  }

  float* ob = out + (size_t)(b << 6) * HW + h * 256 + w;
#pragma unroll
  for (int o = 0; o < 64; ++o) ob[(size_t)o * HW] = acc[o] + b_dcn[o];
}

// Per-(b,o)-plane partial sums -> atomics into sums[64], sumsq[64]
__global__ __launch_bounds__(256) void bn_sums(
    const float* __restrict__ out, float* __restrict__ sums) {
  int p = blockIdx.x;          // 512 planes, plane = b*64+o
  int o = p & 63;
  const float4* pl = (const float4*)(out + (size_t)p * HW);
  float s = 0.f, q = 0.f;
  for (int i = threadIdx.x; i < 16384; i += 256) {
    float4 v = pl[i];
    s += v.x + v.y + v.z + v.w;
    q += v.x * v.x + v.y * v.y + v.z * v.z + v.w * v.w;
  }
#pragma unroll
  for (int off = 32; off > 0; off >>= 1) {
    s += __shfl_down(s, off);
    q += __shfl_down(q, off);
  }
  __shared__ float ls[4], lq[4];
  int wid = threadIdx.x >> 6, lane = threadIdx.x & 63;
  if (lane == 0) { ls[wid] = s; lq[wid] = q; }
  __syncthreads();
  if (threadIdx.x == 0) {
    float S = ls[0] + ls[1] + ls[2] + ls[3];
    float Q = lq[0] + lq[1] + lq[2] + lq[3];
    atomicAdd(&sums[o], S);
    atomicAdd(&sums[64 + o], Q);
  }
}

// In-place: out = relu((out-mean)*rsqrt(var+eps)*gamma + beta)
__global__ __launch_bounds__(256) void bn_apply(
    float* __restrict__ out, const float* __restrict__ sums,
    const float* __restrict__ gamma, const float* __restrict__ beta) {
  int p = blockIdx.x;
  int o = p & 63;
  float mean = sums[o] * (1.f / (float)NPER);
  float var = sums[64 + o] * (1.f / (float)NPER) - mean * mean;
  float inv = rsqrtf(var + 1e-5f);
  float sc = gamma[o] * inv;
  float sh = beta[o] - mean * sc;
  float4* pl = (float4*)(out + (size_t)p * HW);
  for (int i = threadIdx.x; i < 16384; i += 256) {
    float4 v = pl[i];
    v.x = fmaxf(fmaf(v.x, sc, sh), 0.f);
    v.y = fmaxf(fmaf(v.y, sc, sh), 0.f);
    v.z = fmaxf(fmaf(v.z, sc, sh), 0.f);
    v.w = fmaxf(fmaf(v.w, sc, sh), 0.f);
    pl[i] = v;
  }
}

extern "C" void kernel_launch(void* const* d_in, const int* in_sizes, int n_in,
                              void* d_out, int out_size, void* d_ws, size_t ws_size,
                              hipStream_t stream) {
  const float* x     = (const float*)d_in[0];
  const float* w_off = (const float*)d_in[1];
  const float* b_off = (const float*)d_in[2];
  const float* w_dcn = (const float*)d_in[3];
  const float* b_dcn = (const float*)d_in[4];
  const float* gamma = (const float*)d_in[5];
  const float* beta  = (const float*)d_in[6];
  float* out = (float*)d_out;
  float* ws  = (float*)d_ws;

  float* om   = ws + OM_OFF;
  float* sums = ws + SUMS_OFF;
  float* wdT  = ws + WDT_OFF;
  float* wfT  = ws + WFT_OFF;

  hipMemsetAsync(sums, 0, 128 * sizeof(float), stream);
  transpose_wts<<<48, 256, 0, stream>>>(w_off, w_dcn, wfT, wdT);
  offset_conv<<<2048, 256, 0, stream>>>(x, wfT, b_off, om);
  dcn_main<<<2048, 256, 0, stream>>>(x, om, wdT, b_dcn, out);
  bn_sums<<<512, 256, 0, stream>>>(out, sums);
  bn_apply<<<512, 256, 0, stream>>>(out, sums, gamma, beta);
}